// Round 1
// 1318.145 us; speedup vs baseline: 1.0787x; 1.0787x over previous
//
#include <hip/hip_runtime.h>
#include <math.h>

// ---- problem constants ----
constexpr int B_ = 64, L_ = 256, T_ = 32, E_ = 384, H_ = 6;
constexpr int DI_ = 768, DS_ = 16, DC_ = 4, DR_ = 24;
constexpr int HID_ = 1536, V_ = 97, ND_ = 12;
constexpr float EPS_ = 1e-5f;
constexpr int HD_ = 64;

typedef unsigned short ushort_t;
typedef __attribute__((ext_vector_type(8))) short  short8;
typedef __attribute__((ext_vector_type(4))) float  floatx4;
typedef __attribute__((ext_vector_type(8))) unsigned short ushort8v;

__device__ __forceinline__ float siluf(float x) { return x / (1.f + expf(-x)); }
__device__ __forceinline__ float softplusf(float x) {
    return fmaxf(x, 0.f) + log1pf(expf(-fabsf(x)));
}
__device__ __forceinline__ ushort_t f2bf(float f) {
    unsigned int u = __float_as_uint(f);
    u += 0x7fffu + ((u >> 16) & 1u);
    return (ushort_t)(u >> 16);
}
__device__ __forceinline__ float bf2f(ushort_t u) {
    return __uint_as_float(((unsigned int)u) << 16);
}
__device__ __forceinline__ void unpack2(unsigned int w, float& lo, float& hi) {
    lo = __uint_as_float(w << 16);
    hi = __uint_as_float(w & 0xffff0000u);
}
// async global->LDS, 16B per lane; lds dest = wave-uniform base + lane*16
__device__ __forceinline__ void gl_lds16(const ushort_t* g, ushort_t* l) {
    __builtin_amdgcn_global_load_lds(
        (const __attribute__((address_space(1))) unsigned int*)g,
        (__attribute__((address_space(3))) unsigned int*)l, 16, 0, 0);
}

// ---------------------------------------------------------------------------
// fp32 -> bf16 (vectorized, n divisible by 4)
// ---------------------------------------------------------------------------
__global__ __launch_bounds__(256) void cvt_bf16_kernel(
    const float* __restrict__ src, ushort_t* __restrict__ dst, long n4) {
    long i = (long)blockIdx.x * 256 + threadIdx.x;
    if (i >= n4) return;
    float4 v = ((const float4*)src)[i];
    __attribute__((ext_vector_type(4))) unsigned short o;
    o[0] = f2bf(v.x); o[1] = f2bf(v.y); o[2] = f2bf(v.z); o[3] = f2bf(v.w);
    *(__attribute__((ext_vector_type(4))) unsigned short*)(dst + i * 4) = o;
}

// fp32 -> bf16 with per-layer zero padding
__global__ __launch_bounds__(256) void cvt_pad_kernel(
    const float* __restrict__ src, ushort_t* __restrict__ dst,
    int sr, int sc, int dr, int dc, int layers) {
    long total = (long)layers * dr * dc;
    long idx = (long)blockIdx.x * 256 + threadIdx.x;
    if (idx >= total) return;
    int l = (int)(idx / ((long)dr * dc));
    int rem = (int)(idx % ((long)dr * dc));
    int r = rem / dc, c = rem % dc;
    float v = (r < sr && c < sc) ? src[((long)l * sr + r) * sc + c] : 0.f;
    dst[idx] = f2bf(v);
}

// ---------------------------------------------------------------------------
// bf16 MFMA GEMM with global_load_lds staging + XOR swizzle.
// C[m,n] = act( sum_k A[m,k]*W[n,k] + bias[n] ) + addin ; zero-fill N<=gn<Nz.
// A bf16 [M][lda], W bf16 [Nz_rounded][K]. K % 64 == 0, M % 64 == 0.
// ACT: 0 none, 1 relu, 2 softplus. OBF: 1 bf16 out, 0 fp32 out.
// ---------------------------------------------------------------------------
template <int ACT, int OBF>
__global__ __launch_bounds__(256) void gemm_bf16(
    const ushort_t* __restrict__ A, int lda,
    const ushort_t* __restrict__ W,
    const float* __restrict__ bias,
    const float* __restrict__ addin,
    void* __restrict__ Cv,
    int M, int N, int K, int Nz, int ldc) {
    __shared__ ushort_t As[64 * 64];
    __shared__ ushort_t Bs[64 * 64];

    const int tid = threadIdx.x;
    const int wv = tid >> 6, ln = tid & 63;
    const int bm = blockIdx.x * 64, bn = blockIdx.y * 64;
    const int lm = ln & 15, quad = ln >> 4;
    const int wm = (wv & 1) * 32, wn = (wv >> 1) * 32;
    const int r8 = ln >> 3, c8 = ln & 7;

    floatx4 acc[2][2] = {};

    for (int k0 = 0; k0 < K; k0 += 64) {
#pragma unroll
        for (int j = 0; j < 2; ++j) {
            int row = wv * 16 + j * 8 + r8;
            int cg = c8 ^ (row & 7);
            gl_lds16(A + (size_t)(bm + row) * lda + k0 + cg * 8,
                     &As[(wv * 16 + j * 8) * 64]);
        }
#pragma unroll
        for (int j = 0; j < 2; ++j) {
            int row = wv * 16 + j * 8 + r8;
            int cg = c8 ^ (row & 7);
            gl_lds16(W + (size_t)(bn + row) * K + k0 + cg * 8,
                     &Bs[(wv * 16 + j * 8) * 64]);
        }
        __syncthreads();
#pragma unroll
        for (int ks2 = 0; ks2 < 2; ++ks2) {
            int pc = ((quad + ks2 * 4) ^ (lm & 7)) * 8;
            short8 a0 = *(const short8*)&As[(wm + lm) * 64 + pc];
            short8 a1 = *(const short8*)&As[(wm + 16 + lm) * 64 + pc];
            short8 b0 = *(const short8*)&Bs[(wn + lm) * 64 + pc];
            short8 b1 = *(const short8*)&Bs[(wn + 16 + lm) * 64 + pc];
            acc[0][0] = __builtin_amdgcn_mfma_f32_16x16x32_bf16(a0, b0, acc[0][0], 0, 0, 0);
            acc[0][1] = __builtin_amdgcn_mfma_f32_16x16x32_bf16(a0, b1, acc[0][1], 0, 0, 0);
            acc[1][0] = __builtin_amdgcn_mfma_f32_16x16x32_bf16(a1, b0, acc[1][0], 0, 0, 0);
            acc[1][1] = __builtin_amdgcn_mfma_f32_16x16x32_bf16(a1, b1, acc[1][1], 0, 0, 0);
        }
        __syncthreads();
    }

    // C/D layout: col = lane&15, row = quad*4 + reg  [m89-verified]
#pragma unroll
    for (int sm = 0; sm < 2; ++sm) {
#pragma unroll
        for (int sn = 0; sn < 2; ++sn) {
            const int gn = bn + wn + sn * 16 + lm;
            if (gn >= Nz) continue;
#pragma unroll
            for (int r = 0; r < 4; ++r) {
                const int gm = bm + wm + sm * 16 + quad * 4 + r;
                float v;
                if (gn < N) {
                    v = acc[sm][sn][r];
                    if (bias) v += bias[gn];
                    if (ACT == 1) v = fmaxf(v, 0.f);
                    if (ACT == 2) v = softplusf(v);
                    if (addin) v += addin[(size_t)gm * ldc + gn];
                } else {
                    v = 0.f;
                }
                if (OBF)
                    ((ushort_t*)Cv)[(size_t)gm * ldc + gn] = f2bf(v);
                else
                    ((float*)Cv)[(size_t)gm * ldc + gn] = v;
            }
        }
    }
}

// ---------------------------------------------------------------------------
__global__ void init_kernel(const float* __restrict__ qe,
                            const float* __restrict__ pos,
                            float* __restrict__ houtf,
                            float* __restrict__ residual) {
    long idx = (long)blockIdx.x * 256 + threadIdx.x;
    if (idx >= (long)B_ * T_ * E_) return;
    int te = (int)(idx % ((long)T_ * E_));
    houtf[idx] = qe[te] + pos[te];
    residual[idx] = 0.f;
}

// residual += hin; hidden_bf = bf16(rmsnorm(residual) * w)
__global__ __launch_bounds__(256) void add_rmsnorm_kernel(
    const float* __restrict__ hin, float* __restrict__ residual,
    ushort_t* __restrict__ hout, const float* __restrict__ w) {
    const int row = blockIdx.x, tid = threadIdx.x;
    const long base = (long)row * E_;
    __shared__ float red[256];

    float x0 = hin[base + tid] + residual[base + tid];
    bool has1 = (tid + 256 < E_);
    float x1 = has1 ? hin[base + tid + 256] + residual[base + tid + 256] : 0.f;
    residual[base + tid] = x0;
    if (has1) residual[base + tid + 256] = x1;

    red[tid] = x0 * x0 + x1 * x1;
    __syncthreads();
    for (int off = 128; off > 0; off >>= 1) {
        if (tid < off) red[tid] += red[tid + off];
        __syncthreads();
    }
    float sc = rsqrtf(red[0] / E_ + EPS_);
    hout[base + tid] = f2bf(x0 * sc * w[tid]);
    if (has1) hout[base + tid + 256] = f2bf(x1 * sc * w[tid + 256]);
}

// layernorm fp32 in -> bf16 out
__global__ __launch_bounds__(256) void layernorm_kernel(
    const float* __restrict__ x, const float* __restrict__ w,
    const float* __restrict__ b, ushort_t* __restrict__ out) {
    const int row = blockIdx.x, tid = threadIdx.x;
    const long base = (long)row * E_;
    __shared__ float red[256];

    float x0 = x[base + tid];
    bool has1 = (tid + 256 < E_);
    float x1 = has1 ? x[base + tid + 256] : 0.f;

    red[tid] = x0 + x1;
    __syncthreads();
    for (int off = 128; off > 0; off >>= 1) {
        if (tid < off) red[tid] += red[tid + off];
        __syncthreads();
    }
    float mu = red[0] / E_;
    __syncthreads();
    float d0 = x0 - mu, d1 = has1 ? x1 - mu : 0.f;
    red[tid] = d0 * d0 + d1 * d1;
    __syncthreads();
    for (int off = 128; off > 0; off >>= 1) {
        if (tid < off) red[tid] += red[tid + off];
        __syncthreads();
    }
    float sc = rsqrtf(red[0] / E_ + EPS_);
    out[base + tid] = f2bf(d0 * sc * w[tid] + b[tid]);
    if (has1) out[base + tid + 256] = f2bf(d1 * sc * w[tid + 256] + b[tid + 256]);
}

// ---------------------------------------------------------------------------
// depthwise causal conv (DC=4) + bias + SiLU, bf16 in/out, 8 channels/thread
// ---------------------------------------------------------------------------
__global__ __launch_bounds__(256) void conv_silu_kernel(
    const ushort_t* __restrict__ xz, const float* __restrict__ cw,
    const float* __restrict__ cb, ushort_t* __restrict__ xc) {
    int idx = blockIdx.x * 256 + threadIdx.x;  // over B*T*(DI/8)
    if (idx >= B_ * T_ * (DI_ / 8)) return;
    int dc = idx % (DI_ / 8);
    int t = (idx / (DI_ / 8)) % T_;
    int b = idx / ((DI_ / 8) * T_);
    int d0 = dc * 8;

    float4 cwj[8];
#pragma unroll
    for (int j = 0; j < 8; ++j) cwj[j] = *(const float4*)&cw[(d0 + j) * 4];
    float acc[8];
#pragma unroll
    for (int j = 0; j < 8; ++j) acc[j] = cb[d0 + j];

#pragma unroll
    for (int k = 0; k < DC_; ++k) {
        int tt = t + k - (DC_ - 1);
        if (tt < 0) continue;
        uint4 u = *(const uint4*)(xz + (size_t)(b * T_ + tt) * (2 * DI_) + d0);
        float x[8];
        unpack2(u.x, x[0], x[1]); unpack2(u.y, x[2], x[3]);
        unpack2(u.z, x[4], x[5]); unpack2(u.w, x[6], x[7]);
#pragma unroll
        for (int j = 0; j < 8; ++j) {
            float wv = (k == 0) ? cwj[j].x : (k == 1) ? cwj[j].y
                     : (k == 2) ? cwj[j].z : cwj[j].w;
            acc[j] += wv * x[j];
        }
    }
    ushort8v o;
#pragma unroll
    for (int j = 0; j < 8; ++j) o[j] = f2bf(siluf(acc[j]));
    *(ushort8v*)(xc + (size_t)(b * T_ + t) * DI_ + d0) = o;
}

// ---------------------------------------------------------------------------
// selective scan, bf16 I/O; grid (DI/256, B)
// ---------------------------------------------------------------------------
__global__ __launch_bounds__(256) void mamba_scan_kernel(
    const ushort_t* __restrict__ dtb,
    const ushort_t* __restrict__ dbl,
    const ushort_t* __restrict__ xc,
    const ushort_t* __restrict__ xz,
    const float* __restrict__ Alog,
    const float* __restrict__ Dp,
    ushort_t* __restrict__ y) {
    const int d = blockIdx.x * 256 + threadIdx.x;
    const int b = blockIdx.y;
    __shared__ float Bs[T_][DS_];
    __shared__ float Cs[T_][DS_];
    for (int i = threadIdx.x; i < T_ * DS_; i += 256) {
        int t = i >> 4, s = i & 15;
        size_t rb = (size_t)(b * T_ + t) * 64;
        Bs[t][s] = bf2f(dbl[rb + DR_ + s]);
        Cs[t][s] = bf2f(dbl[rb + DR_ + DS_ + s]);
    }
    __syncthreads();

    float Aa[DS_];
#pragma unroll
    for (int s = 0; s < DS_; ++s) Aa[s] = -expf(Alog[(size_t)d * DS_ + s]);
    float h[DS_] = {};
    const float Dv = Dp[d];

    for (int t = 0; t < T_; ++t) {
        size_t idx = (size_t)(b * T_ + t) * DI_ + d;
        float dtv = bf2f(dtb[idx]);
        float xcv = bf2f(xc[idx]);
        float acc = 0.f;
#pragma unroll
        for (int s = 0; s < DS_; ++s) {
            h[s] = __expf(dtv * Aa[s]) * h[s] + dtv * Bs[t][s] * xcv;
            acc += h[s] * Cs[t][s];
        }
        float zv = bf2f(xz[(size_t)(b * T_ + t) * (2 * DI_) + DI_ + d]);
        y[idx] = f2bf((acc + Dv * xcv) * siluf(zv));
    }
}

// ---------------------------------------------------------------------------
// cross-attention, MFMA version: one block per (b,h), 4 waves.
// Fragment layout reuses the verified gemm_bf16 mapping:
//   A/B frag: row = lane&15, k-chunk = quad*8 (+ks*32), 8 contiguous bf16
//   C tile:   col = lane&15, row = quad*4 + reg
// Wave w owns score columns s in [w*64, w*64+64).
// LDS: Vt (V transposed, 264-stride => 2-way free), Pb (bf16 P), partial
// max/sum for cross-wave softmax.  Total ~51.7 KB => 3 blocks/CU.
// ---------------------------------------------------------------------------
__global__ __launch_bounds__(256) void attn_kernel(
    const ushort_t* __restrict__ qh,
    const ushort_t* __restrict__ kh,
    const ushort_t* __restrict__ vh,
    ushort_t* __restrict__ ctx) {
    const int h = blockIdx.x % H_;
    const int b = blockIdx.x / H_;
    const int tid = threadIdx.x;
    const int w = tid >> 6, ln = tid & 63;
    const int lm = ln & 15, quad = ln >> 4;

    __shared__ __attribute__((aligned(16))) ushort_t Vt[64 * 264];  // [d][s]
    __shared__ __attribute__((aligned(16))) ushort_t Pb[32 * 264];  // [t][s]
    __shared__ float rmax[4][32];
    __shared__ float rsum[4][32];

    // ---- Q fragments (registers): rows mt*16+lm, k-chunk ks*32+quad*8 ----
    short8 aq[2][2];
#pragma unroll
    for (int mt = 0; mt < 2; ++mt)
#pragma unroll
        for (int ks = 0; ks < 2; ++ks)
            aq[mt][ks] = *(const short8*)(qh + (size_t)(b * T_ + mt * 16 + lm) * E_ +
                                          h * HD_ + ks * 32 + quad * 8);

    // ---- K fragments (registers) for this wave's s-range ----
    short8 bk[4][2];
#pragma unroll
    for (int nt = 0; nt < 4; ++nt)
#pragma unroll
        for (int ks = 0; ks < 2; ++ks)
            bk[nt][ks] = *(const short8*)(kh + (size_t)(b * L_ + w * 64 + nt * 16 + lm) * E_ +
                                          h * HD_ + ks * 32 + quad * 8);

    // ---- stage V transposed into LDS (paired rows -> b32 writes) ----
    {
        const int sp = tid & 127, dh = tid >> 7;
        const int s0 = sp * 2;
        const ushort_t* vr = vh + (size_t)(b * L_ + s0) * E_ + h * HD_ + dh * 32;
        uint4 va[4], vb[4];
#pragma unroll
        for (int c = 0; c < 4; ++c) {
            va[c] = *(const uint4*)(vr + c * 8);
            vb[c] = *(const uint4*)(vr + E_ + c * 8);
        }
#pragma unroll
        for (int c = 0; c < 4; ++c) {
            const unsigned int* pa = (const unsigned int*)&va[c];
            const unsigned int* pb = (const unsigned int*)&vb[c];
#pragma unroll
            for (int j = 0; j < 4; ++j) {
                int d0 = dh * 32 + c * 8 + j * 2;
                unsigned int lo = (pa[j] & 0xffffu) | (pb[j] << 16);
                unsigned int hi = (pa[j] >> 16) | (pb[j] & 0xffff0000u);
                *(unsigned int*)&Vt[d0 * 264 + s0] = lo;
                *(unsigned int*)&Vt[(d0 + 1) * 264 + s0] = hi;
            }
        }
    }

    // ---- QK^T: 16 MFMA / wave ----
    floatx4 acc[2][4] = {};
#pragma unroll
    for (int ks = 0; ks < 2; ++ks)
#pragma unroll
        for (int mt = 0; mt < 2; ++mt)
#pragma unroll
            for (int nt = 0; nt < 4; ++nt)
                acc[mt][nt] = __builtin_amdgcn_mfma_f32_16x16x32_bf16(
                    aq[mt][ks], bk[nt][ks], acc[mt][nt], 0, 0, 0);
#pragma unroll
    for (int mt = 0; mt < 2; ++mt)
#pragma unroll
        for (int nt = 0; nt < 4; ++nt)
            acc[mt][nt] *= 0.125f;  // 1/sqrt(hd)

    // ---- per-wave row max over this wave's 64 columns ----
    float mpart[2][4];
#pragma unroll
    for (int mt = 0; mt < 2; ++mt)
#pragma unroll
        for (int r = 0; r < 4; ++r) {
            float m = fmaxf(fmaxf(acc[mt][0][r], acc[mt][1][r]),
                            fmaxf(acc[mt][2][r], acc[mt][3][r]));
#pragma unroll
            for (int mk = 1; mk < 16; mk <<= 1)
                m = fmaxf(m, __shfl_xor(m, mk, 64));
            mpart[mt][r] = m;
        }
    if (lm == 0) {
#pragma unroll
        for (int mt = 0; mt < 2; ++mt)
#pragma unroll
            for (int r = 0; r < 4; ++r)
                rmax[w][mt * 16 + quad * 4 + r] = mpart[mt][r];
    }
    __syncthreads();

    // ---- exp(score - gmax), partial sums, write P (bf16) ----
    float spart[2][4];
#pragma unroll
    for (int mt = 0; mt < 2; ++mt)
#pragma unroll
        for (int r = 0; r < 4; ++r) {
            const int t = mt * 16 + quad * 4 + r;
            float gm = fmaxf(fmaxf(rmax[0][t], rmax[1][t]),
                             fmaxf(rmax[2][t], rmax[3][t]));
            float s = 0.f;
#pragma unroll
            for (int nt = 0; nt < 4; ++nt) {
                float e = __expf(acc[mt][nt][r] - gm);
                s += e;
                Pb[t * 264 + w * 64 + nt * 16 + lm] = f2bf(e);
            }
#pragma unroll
            for (int mk = 1; mk < 16; mk <<= 1)
                s += __shfl_xor(s, mk, 64);
            spart[mt][r] = s;
        }
    if (lm == 0) {
#pragma unroll
        for (int mt = 0; mt < 2; ++mt)
#pragma unroll
            for (int r = 0; r < 4; ++r)
                rsum[w][mt * 16 + quad * 4 + r] = spart[mt][r];
    }
    __syncthreads();

    // ---- PV: wave w computes m-tile (w&1), d-tiles {2*(w>>1), 2*(w>>1)+1} ----
    const int mt = w & 1, nth = w >> 1;
    floatx4 pacc[2] = {};
#pragma unroll
    for (int ks = 0; ks < 8; ++ks) {
        short8 pa = *(const short8*)&Pb[(mt * 16 + lm) * 264 + ks * 32 + quad * 8];
#pragma unroll
        for (int i = 0; i < 2; ++i) {
            short8 vb = *(const short8*)&Vt[((nth * 2 + i) * 16 + lm) * 264 + ks * 32 + quad * 8];
            pacc[i] = __builtin_amdgcn_mfma_f32_16x16x32_bf16(pa, vb, pacc[i], 0, 0, 0);
        }
    }

    // ---- epilogue: scale by 1/sum, store bf16 ----
#pragma unroll
    for (int r = 0; r < 4; ++r) {
        const int t = mt * 16 + quad * 4 + r;
        float dn = 1.f / (rsum[0][t] + rsum[1][t] + rsum[2][t] + rsum[3][t]);
#pragma unroll
        for (int i = 0; i < 2; ++i) {
            const int d = (nth * 2 + i) * 16 + lm;
            ctx[(size_t)(b * T_ + t) * E_ + h * HD_ + d] = f2bf(pacc[i][r] * dn);
        }
    }
}

// ---------------------------------------------------------------------------
static void gemm(hipStream_t s, int act, int obf, const ushort_t* A, int lda,
                 const ushort_t* W, const float* bias, const float* addin,
                 void* C, int M, int N, int K, int Nz, int ldc) {
    dim3 g(M / 64, (Nz + 63) / 64), b(256);
    if (obf) {
        switch (act) {
            case 0: gemm_bf16<0, 1><<<g, b, 0, s>>>(A, lda, W, bias, addin, C, M, N, K, Nz, ldc); break;
            case 1: gemm_bf16<1, 1><<<g, b, 0, s>>>(A, lda, W, bias, addin, C, M, N, K, Nz, ldc); break;
            case 2: gemm_bf16<2, 1><<<g, b, 0, s>>>(A, lda, W, bias, addin, C, M, N, K, Nz, ldc); break;
        }
    } else {
        gemm_bf16<0, 0><<<g, b, 0, s>>>(A, lda, W, bias, addin, C, M, N, K, Nz, ldc);
    }
}

static void cvt(hipStream_t s, const float* src, ushort_t* dst, long n) {
    long n4 = n / 4;
    cvt_bf16_kernel<<<(int)((n4 + 255) / 256), 256, 0, s>>>(src, dst, n4);
}
static void cvt_pad(hipStream_t s, const float* src, ushort_t* dst,
                    int sr, int sc, int dr, int dc, int layers) {
    long total = (long)layers * dr * dc;
    cvt_pad_kernel<<<(int)((total + 255) / 256), 256, 0, s>>>(src, dst, sr, sc, dr, dc, layers);
}

extern "C" void kernel_launch(void* const* d_in, const int* in_sizes, int n_in,
                              void* d_out, int out_size, void* d_ws, size_t ws_size,
                              hipStream_t stream) {
    const float* enc      = (const float*)d_in[0];
    const float* qe       = (const float*)d_in[1];
    const float* pos      = (const float*)d_in[2];
    const float* m_norm_w = (const float*)d_in[3];
    const float* m_in_w   = (const float*)d_in[4];
    const float* m_conv_w = (const float*)d_in[5];
    const float* m_conv_b = (const float*)d_in[6];
    const float* m_xproj_w= (const float*)d_in[7];
    const float* m_dt_w   = (const float*)d_in[8];
    const float* m_dt_b   = (const float*)d_in[9];
    const float* m_Alog   = (const float*)d_in[10];
    const float* m_D      = (const float*)d_in[11];
    const float* m_out_w  = (const float*)d_in[12];
    const float* rms_w    = (const float*)d_in[13];
    const float* wq = (const float*)d_in[14];
    const float* bq = (const float*)d_in[15];
    const float* wk = (const float*)d_in[16];
    const float* bk = (const float*)d_in[17];
    const float* wv = (const float*)d_in[18];
    const float* bv = (const float*)d_in[19];
    const float* wo = (const float*)d_in[20];
    const float* bo = (const float*)d_in[21];
    const float* ln1_w = (const float*)d_in[22];
    const float* ln1_b = (const float*)d_in[23];
    const float* ffn_w1 = (const float*)d_in[24];
    const float* ffn_b1 = (const float*)d_in[25];
    const float* ffn_w2 = (const float*)d_in[26];
    const float* ffn_b2 = (const float*)d_in[27];
    const float* ln2_w = (const float*)d_in[28];
    const float* ln2_b = (const float*)d_in[29];
    const float* out_w = (const float*)d_in[30];
    const float* out_b = (const float*)d_in[31];

    const long SZ_BTE = (long)B_ * T_ * E_;  // 786432
    float* residual = (float*)d_ws;
    float* houtf    = residual + SZ_BTE;

    ushort_t* u = (ushort_t*)(houtf + SZ_BTE);
    ushort_t* hidden = u;                    // 786,432
    ushort_t* S      = hidden + SZ_BTE;      // union region, 7,995,392 us
    // mamba-phase layout:
    ushort_t* xz  = S;                       // 3,145,728
    ushort_t* xc  = xz + 3145728;            // 1,572,864
    ushort_t* dbl = xc + 1572864;            //   131,072 (2048 x 64 padded)
    ushort_t* dtb = dbl + 131072;            // 1,572,864
    ushort_t* yb  = dtb + 1572864;           // 1,572,864
    // attention-phase aliases:
    ushort_t* enc_bf = S;                    // 6,291,456
    ushort_t* qh  = S + 6291456;             //   786,432
    ushort_t* ctx = qh + 786432;             //   786,432
    // ffn alias:
    ushort_t* ffnb = S;                      // 3,145,728
    ushort_t* kh = S + 7995392;              // 6,291,456
    ushort_t* vh = kh + 6291456;             // 6,291,456

    // bf16 weights (padded where needed)
    ushort_t* w_in    = vh + 6291456;        // 7,077,888
    ushort_t* w_xproj = w_in + 7077888;      // 12*64*768 (rows 56..63 zero)
    ushort_t* w_dt    = w_xproj + 589824;    // 12*768*64 (cols 24..63 zero)
    ushort_t* w_out   = w_dt + 589824;       // 3,538,944
    ushort_t* w_q     = w_out + 3538944;
    ushort_t* w_k     = w_q + 147456;
    ushort_t* w_v     = w_k + 147456;
    ushort_t* w_o     = w_v + 147456;
    ushort_t* w_f1    = w_o + 147456;
    ushort_t* w_f2    = w_f1 + 589824;
    ushort_t* w_lg    = w_f2 + 589824;       // 128*384 (rows 97..127 zero)

    const int M  = B_ * T_;   // 2048
    const int MK = B_ * L_;   // 16384

    // ---- weight conversion (every launch) ----
    cvt(stream, m_in_w,  w_in,  7077888);
    cvt_pad(stream, m_xproj_w, w_xproj, 56, 768, 64, 768, 12);
    cvt_pad(stream, m_dt_w,    w_dt,    768, 24, 768, 64, 12);
    cvt(stream, m_out_w, w_out, 3538944);
    cvt(stream, wq, w_q, 147456);
    cvt(stream, wk, w_k, 147456);
    cvt(stream, wv, w_v, 147456);
    cvt(stream, wo, w_o, 147456);
    cvt(stream, ffn_w1, w_f1, 589824);
    cvt(stream, ffn_w2, w_f2, 589824);
    cvt_pad(stream, out_w, w_lg, 97, 384, 128, 384, 1);

    init_kernel<<<(int)((SZ_BTE + 255) / 256), 256, 0, stream>>>(qe, pos, houtf, residual);

    for (int l = 0; l < ND_; ++l) {
        add_rmsnorm_kernel<<<M, 256, 0, stream>>>(houtf, residual, hidden,
                                                  m_norm_w + (long)l * E_);
        gemm(stream, 0, 1, hidden, E_, w_in + (long)l * 1536 * 384,
             nullptr, nullptr, xz, M, 1536, 384, 1536, 1536);
        conv_silu_kernel<<<(M * (DI_ / 8) + 255) / 256, 256, 0, stream>>>(
            xz, m_conv_w + (long)l * DI_ * DC_, m_conv_b + (long)l * DI_, xc);
        gemm(stream, 0, 1, xc, DI_, w_xproj + (long)l * 64 * 768,
             nullptr, nullptr, dbl, M, 56, 768, 64, 64);
        gemm(stream, 2, 1, dbl, 64, w_dt + (long)l * 768 * 64,
             m_dt_b + (long)l * DI_, nullptr, dtb, M, 768, 64, 768, 768);
        mamba_scan_kernel<<<dim3(DI_ / 256, B_), 256, 0, stream>>>(
            dtb, dbl, xc, xz, m_Alog + (long)l * DI_ * DS_, m_D + (long)l * DI_, yb);
        gemm(stream, 0, 0, yb, DI_, w_out + (long)l * 384 * 768,
             nullptr, nullptr, houtf, M, 384, 768, 384, 384);
    }

    add_rmsnorm_kernel<<<M, 256, 0, stream>>>(houtf, residual, hidden, rms_w);

    gemm(stream, 0, 1, hidden, E_, w_q, bq, nullptr, qh, M, 384, 384, 384, 384);
    cvt(stream, enc, enc_bf, (long)MK * E_);
    gemm(stream, 0, 1, enc_bf, E_, w_k, bk, nullptr, kh, MK, 384, 384, 384, 384);
    gemm(stream, 0, 1, enc_bf, E_, w_v, bv, nullptr, vh, MK, 384, 384, 384, 384);
    attn_kernel<<<B_ * H_, 256, 0, stream>>>(qh, kh, vh, ctx);
    gemm(stream, 0, 0, ctx, E_, w_o, bo, residual, residual, M, 384, 384, 384, 384);

    layernorm_kernel<<<M, 256, 0, stream>>>(residual, ln1_w, ln1_b, hidden);
    gemm(stream, 1, 1, hidden, E_, w_f1, ffn_b1, nullptr, ffnb, M, 1536, 384, 1536, 1536);
    gemm(stream, 0, 0, ffnb, HID_, w_f2, ffn_b2, residual, residual, M, 384, 1536, 384, 384);
    layernorm_kernel<<<M, 256, 0, stream>>>(residual, ln2_w, ln2_b, hidden);

    gemm(stream, 0, 0, hidden, E_, w_lg, out_b, nullptr, (float*)d_out, M, V_, 384, V_, V_);
}

// Round 2
// 1241.104 us; speedup vs baseline: 1.1457x; 1.0621x over previous
//
#include <hip/hip_runtime.h>
#include <math.h>

// ---- problem constants ----
constexpr int B_ = 64, L_ = 256, T_ = 32, E_ = 384, H_ = 6;
constexpr int DI_ = 768, DS_ = 16, DC_ = 4, DR_ = 24;
constexpr int HID_ = 1536, V_ = 97, ND_ = 12;
constexpr float EPS_ = 1e-5f;
constexpr int HD_ = 64;

typedef unsigned short ushort_t;
typedef __attribute__((ext_vector_type(8))) short  short8;
typedef __attribute__((ext_vector_type(4))) float  floatx4;
typedef __attribute__((ext_vector_type(8))) unsigned short ushort8v;

__device__ __forceinline__ float siluf(float x) { return x / (1.f + __expf(-x)); }
__device__ __forceinline__ float softplusf(float x) {
    return fmaxf(x, 0.f) + log1pf(expf(-fabsf(x)));
}
__device__ __forceinline__ ushort_t f2bf(float f) {
    unsigned int u = __float_as_uint(f);
    u += 0x7fffu + ((u >> 16) & 1u);
    return (ushort_t)(u >> 16);
}
__device__ __forceinline__ float bf2f(ushort_t u) {
    return __uint_as_float(((unsigned int)u) << 16);
}
__device__ __forceinline__ void unpack2(unsigned int w, float& lo, float& hi) {
    lo = __uint_as_float(w << 16);
    hi = __uint_as_float(w & 0xffff0000u);
}
// async global->LDS, 16B per lane; lds dest = wave-uniform base + lane*16
__device__ __forceinline__ void gl_lds16(const ushort_t* g, ushort_t* l) {
    __builtin_amdgcn_global_load_lds(
        (const __attribute__((address_space(1))) unsigned int*)g,
        (__attribute__((address_space(3))) unsigned int*)l, 16, 0, 0);
}

// ---------------------------------------------------------------------------
// fp32 -> bf16 (vectorized, n divisible by 4)
// ---------------------------------------------------------------------------
__global__ __launch_bounds__(256) void cvt_bf16_kernel(
    const float* __restrict__ src, ushort_t* __restrict__ dst, long n4) {
    long i = (long)blockIdx.x * 256 + threadIdx.x;
    if (i >= n4) return;
    float4 v = ((const float4*)src)[i];
    __attribute__((ext_vector_type(4))) unsigned short o;
    o[0] = f2bf(v.x); o[1] = f2bf(v.y); o[2] = f2bf(v.z); o[3] = f2bf(v.w);
    *(__attribute__((ext_vector_type(4))) unsigned short*)(dst + i * 4) = o;
}

// fp32 -> bf16 with per-layer zero padding
__global__ __launch_bounds__(256) void cvt_pad_kernel(
    const float* __restrict__ src, ushort_t* __restrict__ dst,
    int sr, int sc, int dr, int dc, int layers) {
    long total = (long)layers * dr * dc;
    long idx = (long)blockIdx.x * 256 + threadIdx.x;
    if (idx >= total) return;
    int l = (int)(idx / ((long)dr * dc));
    int rem = (int)(idx % ((long)dr * dc));
    int r = rem / dc, c = rem % dc;
    float v = (r < sr && c < sc) ? src[((long)l * sr + r) * sc + c] : 0.f;
    dst[idx] = f2bf(v);
}

// ---------------------------------------------------------------------------
// bf16 MFMA GEMM with global_load_lds staging + XOR swizzle.
// C[m,n] = act( sum_k A[m,k]*W[n,k] + bias[n] ) + addin ; zero-fill N<=gn<Nz.
// A bf16 [M][lda], W bf16 [Nz_rounded][K]. K % 64 == 0, M % 64 == 0.
// ACT: 0 none, 1 relu, 2 softplus. OBF: 1 bf16 out, 0 fp32 out.
// ---------------------------------------------------------------------------
template <int ACT, int OBF>
__global__ __launch_bounds__(256) void gemm_bf16(
    const ushort_t* __restrict__ A, int lda,
    const ushort_t* __restrict__ W,
    const float* __restrict__ bias,
    const float* __restrict__ addin,
    void* __restrict__ Cv,
    int M, int N, int K, int Nz, int ldc) {
    __shared__ ushort_t As[64 * 64];
    __shared__ ushort_t Bs[64 * 64];

    const int tid = threadIdx.x;
    const int wv = tid >> 6, ln = tid & 63;
    const int bm = blockIdx.x * 64, bn = blockIdx.y * 64;
    const int lm = ln & 15, quad = ln >> 4;
    const int wm = (wv & 1) * 32, wn = (wv >> 1) * 32;
    const int r8 = ln >> 3, c8 = ln & 7;

    floatx4 acc[2][2] = {};

    for (int k0 = 0; k0 < K; k0 += 64) {
#pragma unroll
        for (int j = 0; j < 2; ++j) {
            int row = wv * 16 + j * 8 + r8;
            int cg = c8 ^ (row & 7);
            gl_lds16(A + (size_t)(bm + row) * lda + k0 + cg * 8,
                     &As[(wv * 16 + j * 8) * 64]);
        }
#pragma unroll
        for (int j = 0; j < 2; ++j) {
            int row = wv * 16 + j * 8 + r8;
            int cg = c8 ^ (row & 7);
            gl_lds16(W + (size_t)(bn + row) * K + k0 + cg * 8,
                     &Bs[(wv * 16 + j * 8) * 64]);
        }
        __syncthreads();
#pragma unroll
        for (int ks2 = 0; ks2 < 2; ++ks2) {
            int pc = ((quad + ks2 * 4) ^ (lm & 7)) * 8;
            short8 a0 = *(const short8*)&As[(wm + lm) * 64 + pc];
            short8 a1 = *(const short8*)&As[(wm + 16 + lm) * 64 + pc];
            short8 b0 = *(const short8*)&Bs[(wn + lm) * 64 + pc];
            short8 b1 = *(const short8*)&Bs[(wn + 16 + lm) * 64 + pc];
            acc[0][0] = __builtin_amdgcn_mfma_f32_16x16x32_bf16(a0, b0, acc[0][0], 0, 0, 0);
            acc[0][1] = __builtin_amdgcn_mfma_f32_16x16x32_bf16(a0, b1, acc[0][1], 0, 0, 0);
            acc[1][0] = __builtin_amdgcn_mfma_f32_16x16x32_bf16(a1, b0, acc[1][0], 0, 0, 0);
            acc[1][1] = __builtin_amdgcn_mfma_f32_16x16x32_bf16(a1, b1, acc[1][1], 0, 0, 0);
        }
        __syncthreads();
    }

    // C/D layout: col = lane&15, row = quad*4 + reg  [m89-verified]
#pragma unroll
    for (int sm = 0; sm < 2; ++sm) {
#pragma unroll
        for (int sn = 0; sn < 2; ++sn) {
            const int gn = bn + wn + sn * 16 + lm;
            if (gn >= Nz) continue;
#pragma unroll
            for (int r = 0; r < 4; ++r) {
                const int gm = bm + wm + sm * 16 + quad * 4 + r;
                float v;
                if (gn < N) {
                    v = acc[sm][sn][r];
                    if (bias) v += bias[gn];
                    if (ACT == 1) v = fmaxf(v, 0.f);
                    if (ACT == 2) v = softplusf(v);
                    if (addin) v += addin[(size_t)gm * ldc + gn];
                } else {
                    v = 0.f;
                }
                if (OBF)
                    ((ushort_t*)Cv)[(size_t)gm * ldc + gn] = f2bf(v);
                else
                    ((float*)Cv)[(size_t)gm * ldc + gn] = v;
            }
        }
    }
}

// ---------------------------------------------------------------------------
// in_proj GEMM (M=2048, N=1536, K=384) with FUSED causal conv (DC=4) + SiLU.
// Tile rows are 64 = 2 full batches (T=32, bm%32==0), so the causal conv is
// fully block-local (taps t-3..t never cross the tile). xm-half tiles
// (bn < DI_) round-trip fp32 acc through LDS, convolve, and write xc.
// z-half tiles (bn >= DI_) write bf16 into xz (ldc 1536) as before.
// ---------------------------------------------------------------------------
__global__ __launch_bounds__(256) void gemm_in_conv(
    const ushort_t* __restrict__ A,      // hidden bf16 [2048][384]
    const ushort_t* __restrict__ W,      // w_in layer  [1536][384]
    const float* __restrict__ cw,        // conv weight [768][4]
    const float* __restrict__ cb,        // conv bias   [768]
    ushort_t* __restrict__ xz,           // [2048][1536] (z half used)
    ushort_t* __restrict__ xc) {         // [2048][768]
    __shared__ ushort_t As[64 * 64];
    __shared__ ushort_t Bs[64 * 64];
    __shared__ float Cb[64][65];
    __shared__ float Cw[64][4];
    __shared__ float Cbias[64];

    const int tid = threadIdx.x;
    const int wv = tid >> 6, ln = tid & 63;
    const int bm = blockIdx.x * 64, bn = blockIdx.y * 64;
    const int lm = ln & 15, quad = ln >> 4;
    const int wm = (wv & 1) * 32, wn = (wv >> 1) * 32;
    const int r8 = ln >> 3, c8 = ln & 7;
    const bool is_xm = (bn < DI_);

    if (is_xm && tid < 64) {
        *(float4*)&Cw[tid][0] = *(const float4*)&cw[(bn + tid) * 4];
        Cbias[tid] = cb[bn + tid];
    }

    floatx4 acc[2][2] = {};

    for (int k0 = 0; k0 < E_; k0 += 64) {
#pragma unroll
        for (int j = 0; j < 2; ++j) {
            int row = wv * 16 + j * 8 + r8;
            int cg = c8 ^ (row & 7);
            gl_lds16(A + (size_t)(bm + row) * E_ + k0 + cg * 8,
                     &As[(wv * 16 + j * 8) * 64]);
        }
#pragma unroll
        for (int j = 0; j < 2; ++j) {
            int row = wv * 16 + j * 8 + r8;
            int cg = c8 ^ (row & 7);
            gl_lds16(W + (size_t)(bn + row) * E_ + k0 + cg * 8,
                     &Bs[(wv * 16 + j * 8) * 64]);
        }
        __syncthreads();
#pragma unroll
        for (int ks2 = 0; ks2 < 2; ++ks2) {
            int pc = ((quad + ks2 * 4) ^ (lm & 7)) * 8;
            short8 a0 = *(const short8*)&As[(wm + lm) * 64 + pc];
            short8 a1 = *(const short8*)&As[(wm + 16 + lm) * 64 + pc];
            short8 b0 = *(const short8*)&Bs[(wn + lm) * 64 + pc];
            short8 b1 = *(const short8*)&Bs[(wn + 16 + lm) * 64 + pc];
            acc[0][0] = __builtin_amdgcn_mfma_f32_16x16x32_bf16(a0, b0, acc[0][0], 0, 0, 0);
            acc[0][1] = __builtin_amdgcn_mfma_f32_16x16x32_bf16(a0, b1, acc[0][1], 0, 0, 0);
            acc[1][0] = __builtin_amdgcn_mfma_f32_16x16x32_bf16(a1, b0, acc[1][0], 0, 0, 0);
            acc[1][1] = __builtin_amdgcn_mfma_f32_16x16x32_bf16(a1, b1, acc[1][1], 0, 0, 0);
        }
        __syncthreads();
    }

    if (is_xm) {
        // fp32 tile -> LDS
#pragma unroll
        for (int sm = 0; sm < 2; ++sm)
#pragma unroll
            for (int sn = 0; sn < 2; ++sn)
#pragma unroll
                for (int r = 0; r < 4; ++r)
                    Cb[wm + sm * 16 + quad * 4 + r][wn + sn * 16 + lm] = acc[sm][sn][r];
        __syncthreads();
        // conv + silu: thread -> (row r, 16 channels starting c0)
        const int r = tid >> 2, c0 = (tid & 3) * 16;
        const int tl = r & 31;  // within-batch time index
        ushort_t pk[16];
#pragma unroll
        for (int j = 0; j < 16; ++j) {
            const int c = c0 + j;
            float a = Cbias[c];
#pragma unroll
            for (int k = 0; k < DC_; ++k) {
                int rr = tl + k - (DC_ - 1);
                if (rr >= 0) a += Cw[c][k] * Cb[r + k - (DC_ - 1)][c];
            }
            pk[j] = f2bf(siluf(a));
        }
        ushort_t* dst = xc + (size_t)(bm + r) * DI_ + bn + c0;
        *(ushort8v*)dst = *(ushort8v*)&pk[0];
        *(ushort8v*)(dst + 8) = *(ushort8v*)&pk[8];
    } else {
        // z half -> xz (bf16, ldc 1536)
#pragma unroll
        for (int sm = 0; sm < 2; ++sm)
#pragma unroll
            for (int sn = 0; sn < 2; ++sn) {
                const int gn = bn + wn + sn * 16 + lm;
#pragma unroll
                for (int r = 0; r < 4; ++r) {
                    const int gm = bm + wm + sm * 16 + quad * 4 + r;
                    xz[(size_t)gm * 1536 + gn] = f2bf(acc[sm][sn][r]);
                }
            }
    }
}

// ---------------------------------------------------------------------------
__global__ void init_kernel(const float* __restrict__ qe,
                            const float* __restrict__ pos,
                            float* __restrict__ houtf,
                            float* __restrict__ residual) {
    long idx = (long)blockIdx.x * 256 + threadIdx.x;
    if (idx >= (long)B_ * T_ * E_) return;
    int te = (int)(idx % ((long)T_ * E_));
    houtf[idx] = qe[te] + pos[te];
    residual[idx] = 0.f;
}

// residual += hin; hidden_bf = bf16(rmsnorm(residual) * w)  (shuffle reduce)
__global__ __launch_bounds__(256) void add_rmsnorm_kernel(
    const float* __restrict__ hin, float* __restrict__ residual,
    ushort_t* __restrict__ hout, const float* __restrict__ w) {
    const int row = blockIdx.x, tid = threadIdx.x;
    const long base = (long)row * E_;
    __shared__ float ws[4];

    float x0 = hin[base + tid] + residual[base + tid];
    bool has1 = (tid + 256 < E_);
    float x1 = has1 ? hin[base + tid + 256] + residual[base + tid + 256] : 0.f;
    residual[base + tid] = x0;
    if (has1) residual[base + tid + 256] = x1;

    float p = x0 * x0 + x1 * x1;
#pragma unroll
    for (int m = 1; m < 64; m <<= 1) p += __shfl_xor(p, m, 64);
    if ((tid & 63) == 0) ws[tid >> 6] = p;
    __syncthreads();
    float sc = rsqrtf((ws[0] + ws[1] + ws[2] + ws[3]) / E_ + EPS_);
    hout[base + tid] = f2bf(x0 * sc * w[tid]);
    if (has1) hout[base + tid + 256] = f2bf(x1 * sc * w[tid + 256]);
}

// layernorm fp32 in -> bf16 out (shuffle reduce)
__global__ __launch_bounds__(256) void layernorm_kernel(
    const float* __restrict__ x, const float* __restrict__ w,
    const float* __restrict__ b, ushort_t* __restrict__ out) {
    const int row = blockIdx.x, tid = threadIdx.x;
    const long base = (long)row * E_;
    __shared__ float wa[4], wb[4];

    float x0 = x[base + tid];
    bool has1 = (tid + 256 < E_);
    float x1 = has1 ? x[base + tid + 256] : 0.f;

    float p = x0 + x1;
#pragma unroll
    for (int m = 1; m < 64; m <<= 1) p += __shfl_xor(p, m, 64);
    if ((tid & 63) == 0) wa[tid >> 6] = p;
    __syncthreads();
    float mu = (wa[0] + wa[1] + wa[2] + wa[3]) / E_;

    float d0 = x0 - mu, d1 = has1 ? x1 - mu : 0.f;
    float q = d0 * d0 + d1 * d1;
#pragma unroll
    for (int m = 1; m < 64; m <<= 1) q += __shfl_xor(q, m, 64);
    if ((tid & 63) == 0) wb[tid >> 6] = q;
    __syncthreads();
    float sc = rsqrtf((wb[0] + wb[1] + wb[2] + wb[3]) / E_ + EPS_);
    out[base + tid] = f2bf(d0 * sc * w[tid] + b[tid]);
    if (has1) out[base + tid + 256] = f2bf(d1 * sc * w[tid + 256] + b[tid + 256]);
}

// ---------------------------------------------------------------------------
// selective scan, bf16 I/O; grid (DI/256, B)
// ---------------------------------------------------------------------------
__global__ __launch_bounds__(256) void mamba_scan_kernel(
    const ushort_t* __restrict__ dtb,
    const ushort_t* __restrict__ dbl,
    const ushort_t* __restrict__ xc,
    const ushort_t* __restrict__ xz,
    const float* __restrict__ Alog,
    const float* __restrict__ Dp,
    ushort_t* __restrict__ y) {
    const int d = blockIdx.x * 256 + threadIdx.x;
    const int b = blockIdx.y;
    __shared__ float Bs[T_][DS_];
    __shared__ float Cs[T_][DS_];
    for (int i = threadIdx.x; i < T_ * DS_; i += 256) {
        int t = i >> 4, s = i & 15;
        size_t rb = (size_t)(b * T_ + t) * 64;
        Bs[t][s] = bf2f(dbl[rb + DR_ + s]);
        Cs[t][s] = bf2f(dbl[rb + DR_ + DS_ + s]);
    }
    __syncthreads();

    float Aa[DS_];
#pragma unroll
    for (int s = 0; s < DS_; ++s) Aa[s] = -expf(Alog[(size_t)d * DS_ + s]);
    float h[DS_] = {};
    const float Dv = Dp[d];

    for (int t = 0; t < T_; ++t) {
        size_t idx = (size_t)(b * T_ + t) * DI_ + d;
        float dtv = bf2f(dtb[idx]);
        float xcv = bf2f(xc[idx]);
        float acc = 0.f;
#pragma unroll
        for (int s = 0; s < DS_; ++s) {
            h[s] = __expf(dtv * Aa[s]) * h[s] + dtv * Bs[t][s] * xcv;
            acc += h[s] * Cs[t][s];
        }
        float zv = bf2f(xz[(size_t)(b * T_ + t) * (2 * DI_) + DI_ + d]);
        y[idx] = f2bf((acc + Dv * xcv) * siluf(zv));
    }
}

// ---------------------------------------------------------------------------
// cross-attention, MFMA version: one block per (b,h), 4 waves.
// ---------------------------------------------------------------------------
__global__ __launch_bounds__(256) void attn_kernel(
    const ushort_t* __restrict__ qh,
    const ushort_t* __restrict__ kh,
    const ushort_t* __restrict__ vh,
    ushort_t* __restrict__ ctx) {
    const int h = blockIdx.x % H_;
    const int b = blockIdx.x / H_;
    const int tid = threadIdx.x;
    const int w = tid >> 6, ln = tid & 63;
    const int lm = ln & 15, quad = ln >> 4;

    __shared__ __attribute__((aligned(16))) ushort_t Vt[64 * 264];  // [d][s]
    __shared__ __attribute__((aligned(16))) ushort_t Pb[32 * 264];  // [t][s]
    __shared__ float rmax[4][32];
    __shared__ float rsum[4][32];

    short8 aq[2][2];
#pragma unroll
    for (int mt = 0; mt < 2; ++mt)
#pragma unroll
        for (int ks = 0; ks < 2; ++ks)
            aq[mt][ks] = *(const short8*)(qh + (size_t)(b * T_ + mt * 16 + lm) * E_ +
                                          h * HD_ + ks * 32 + quad * 8);

    short8 bk[4][2];
#pragma unroll
    for (int nt = 0; nt < 4; ++nt)
#pragma unroll
        for (int ks = 0; ks < 2; ++ks)
            bk[nt][ks] = *(const short8*)(kh + (size_t)(b * L_ + w * 64 + nt * 16 + lm) * E_ +
                                          h * HD_ + ks * 32 + quad * 8);

    {
        const int sp = tid & 127, dh = tid >> 7;
        const int s0 = sp * 2;
        const ushort_t* vr = vh + (size_t)(b * L_ + s0) * E_ + h * HD_ + dh * 32;
        uint4 va[4], vb[4];
#pragma unroll
        for (int c = 0; c < 4; ++c) {
            va[c] = *(const uint4*)(vr + c * 8);
            vb[c] = *(const uint4*)(vr + E_ + c * 8);
        }
#pragma unroll
        for (int c = 0; c < 4; ++c) {
            const unsigned int* pa = (const unsigned int*)&va[c];
            const unsigned int* pb = (const unsigned int*)&vb[c];
#pragma unroll
            for (int j = 0; j < 4; ++j) {
                int d0 = dh * 32 + c * 8 + j * 2;
                unsigned int lo = (pa[j] & 0xffffu) | (pb[j] << 16);
                unsigned int hi = (pa[j] >> 16) | (pb[j] & 0xffff0000u);
                *(unsigned int*)&Vt[d0 * 264 + s0] = lo;
                *(unsigned int*)&Vt[(d0 + 1) * 264 + s0] = hi;
            }
        }
    }

    floatx4 acc[2][4] = {};
#pragma unroll
    for (int ks = 0; ks < 2; ++ks)
#pragma unroll
        for (int mt = 0; mt < 2; ++mt)
#pragma unroll
            for (int nt = 0; nt < 4; ++nt)
                acc[mt][nt] = __builtin_amdgcn_mfma_f32_16x16x32_bf16(
                    aq[mt][ks], bk[nt][ks], acc[mt][nt], 0, 0, 0);
#pragma unroll
    for (int mt = 0; mt < 2; ++mt)
#pragma unroll
        for (int nt = 0; nt < 4; ++nt)
            acc[mt][nt] *= 0.125f;

    float mpart[2][4];
#pragma unroll
    for (int mt = 0; mt < 2; ++mt)
#pragma unroll
        for (int r = 0; r < 4; ++r) {
            float m = fmaxf(fmaxf(acc[mt][0][r], acc[mt][1][r]),
                            fmaxf(acc[mt][2][r], acc[mt][3][r]));
#pragma unroll
            for (int mk = 1; mk < 16; mk <<= 1)
                m = fmaxf(m, __shfl_xor(m, mk, 64));
            mpart[mt][r] = m;
        }
    if (lm == 0) {
#pragma unroll
        for (int mt = 0; mt < 2; ++mt)
#pragma unroll
            for (int r = 0; r < 4; ++r)
                rmax[w][mt * 16 + quad * 4 + r] = mpart[mt][r];
    }
    __syncthreads();

    float spart[2][4];
#pragma unroll
    for (int mt = 0; mt < 2; ++mt)
#pragma unroll
        for (int r = 0; r < 4; ++r) {
            const int t = mt * 16 + quad * 4 + r;
            float gm = fmaxf(fmaxf(rmax[0][t], rmax[1][t]),
                             fmaxf(rmax[2][t], rmax[3][t]));
            float s = 0.f;
#pragma unroll
            for (int nt = 0; nt < 4; ++nt) {
                float e = __expf(acc[mt][nt][r] - gm);
                s += e;
                Pb[t * 264 + w * 64 + nt * 16 + lm] = f2bf(e);
            }
#pragma unroll
            for (int mk = 1; mk < 16; mk <<= 1)
                s += __shfl_xor(s, mk, 64);
            spart[mt][r] = s;
        }
    if (lm == 0) {
#pragma unroll
        for (int mt = 0; mt < 2; ++mt)
#pragma unroll
            for (int r = 0; r < 4; ++r)
                rsum[w][mt * 16 + quad * 4 + r] = spart[mt][r];
    }
    __syncthreads();

    const int mt = w & 1, nth = w >> 1;
    floatx4 pacc[2] = {};
#pragma unroll
    for (int ks = 0; ks < 8; ++ks) {
        short8 pa = *(const short8*)&Pb[(mt * 16 + lm) * 264 + ks * 32 + quad * 8];
#pragma unroll
        for (int i = 0; i < 2; ++i) {
            short8 vb = *(const short8*)&Vt[((nth * 2 + i) * 16 + lm) * 264 + ks * 32 + quad * 8];
            pacc[i] = __builtin_amdgcn_mfma_f32_16x16x32_bf16(pa, vb, pacc[i], 0, 0, 0);
        }
    }

#pragma unroll
    for (int r = 0; r < 4; ++r) {
        const int t = mt * 16 + quad * 4 + r;
        float dn = 1.f / (rsum[0][t] + rsum[1][t] + rsum[2][t] + rsum[3][t]);
#pragma unroll
        for (int i = 0; i < 2; ++i) {
            const int d = (nth * 2 + i) * 16 + lm;
            ctx[(size_t)(b * T_ + t) * E_ + h * HD_ + d] = f2bf(pacc[i][r] * dn);
        }
    }
}

// ---------------------------------------------------------------------------
static void gemm(hipStream_t s, int act, int obf, const ushort_t* A, int lda,
                 const ushort_t* W, const float* bias, const float* addin,
                 void* C, int M, int N, int K, int Nz, int ldc) {
    dim3 g(M / 64, (Nz + 63) / 64), b(256);
    if (obf) {
        switch (act) {
            case 0: gemm_bf16<0, 1><<<g, b, 0, s>>>(A, lda, W, bias, addin, C, M, N, K, Nz, ldc); break;
            case 1: gemm_bf16<1, 1><<<g, b, 0, s>>>(A, lda, W, bias, addin, C, M, N, K, Nz, ldc); break;
            case 2: gemm_bf16<2, 1><<<g, b, 0, s>>>(A, lda, W, bias, addin, C, M, N, K, Nz, ldc); break;
        }
    } else {
        gemm_bf16<0, 0><<<g, b, 0, s>>>(A, lda, W, bias, addin, C, M, N, K, Nz, ldc);
    }
}

static void cvt(hipStream_t s, const float* src, ushort_t* dst, long n) {
    long n4 = n / 4;
    cvt_bf16_kernel<<<(int)((n4 + 255) / 256), 256, 0, s>>>(src, dst, n4);
}
static void cvt_pad(hipStream_t s, const float* src, ushort_t* dst,
                    int sr, int sc, int dr, int dc, int layers) {
    long total = (long)layers * dr * dc;
    cvt_pad_kernel<<<(int)((total + 255) / 256), 256, 0, s>>>(src, dst, sr, sc, dr, dc, layers);
}

extern "C" void kernel_launch(void* const* d_in, const int* in_sizes, int n_in,
                              void* d_out, int out_size, void* d_ws, size_t ws_size,
                              hipStream_t stream) {
    const float* enc      = (const float*)d_in[0];
    const float* qe       = (const float*)d_in[1];
    const float* pos      = (const float*)d_in[2];
    const float* m_norm_w = (const float*)d_in[3];
    const float* m_in_w   = (const float*)d_in[4];
    const float* m_conv_w = (const float*)d_in[5];
    const float* m_conv_b = (const float*)d_in[6];
    const float* m_xproj_w= (const float*)d_in[7];
    const float* m_dt_w   = (const float*)d_in[8];
    const float* m_dt_b   = (const float*)d_in[9];
    const float* m_Alog   = (const float*)d_in[10];
    const float* m_D      = (const float*)d_in[11];
    const float* m_out_w  = (const float*)d_in[12];
    const float* rms_w    = (const float*)d_in[13];
    const float* wq = (const float*)d_in[14];
    const float* bq = (const float*)d_in[15];
    const float* wk = (const float*)d_in[16];
    const float* bk = (const float*)d_in[17];
    const float* wv = (const float*)d_in[18];
    const float* bv = (const float*)d_in[19];
    const float* wo = (const float*)d_in[20];
    const float* bo = (const float*)d_in[21];
    const float* ln1_w = (const float*)d_in[22];
    const float* ln1_b = (const float*)d_in[23];
    const float* ffn_w1 = (const float*)d_in[24];
    const float* ffn_b1 = (const float*)d_in[25];
    const float* ffn_w2 = (const float*)d_in[26];
    const float* ffn_b2 = (const float*)d_in[27];
    const float* ln2_w = (const float*)d_in[28];
    const float* ln2_b = (const float*)d_in[29];
    const float* out_w = (const float*)d_in[30];
    const float* out_b = (const float*)d_in[31];

    const long SZ_BTE = (long)B_ * T_ * E_;  // 786432
    float* residual = (float*)d_ws;
    float* houtf    = residual + SZ_BTE;

    ushort_t* u = (ushort_t*)(houtf + SZ_BTE);
    ushort_t* hidden = u;                    // 786,432
    ushort_t* S      = hidden + SZ_BTE;      // union region
    // mamba-phase layout:
    ushort_t* xz  = S;                       // 3,145,728
    ushort_t* xc  = xz + 3145728;            // 1,572,864
    ushort_t* dbl = xc + 1572864;            //   131,072 (2048 x 64 padded)
    ushort_t* dtb = dbl + 131072;            // 1,572,864
    ushort_t* yb  = dtb + 1572864;           // 1,572,864
    // attention-phase aliases:
    ushort_t* enc_bf = S;                    // 6,291,456
    ushort_t* qh  = S + 6291456;             //   786,432
    ushort_t* ctx = qh + 786432;             //   786,432
    // ffn alias:
    ushort_t* ffnb = S;                      // 3,145,728
    ushort_t* kh = S + 7995392;              // 6,291,456
    ushort_t* vh = kh + 6291456;             // 6,291,456

    // bf16 weights (padded where needed)
    ushort_t* w_in    = vh + 6291456;        // 7,077,888
    ushort_t* w_xproj = w_in + 7077888;      // 12*64*768 (rows 56..63 zero)
    ushort_t* w_dt    = w_xproj + 589824;    // 12*768*64 (cols 24..63 zero)
    ushort_t* w_out   = w_dt + 589824;       // 3,538,944
    ushort_t* w_q     = w_out + 3538944;
    ushort_t* w_k     = w_q + 147456;
    ushort_t* w_v     = w_k + 147456;
    ushort_t* w_o     = w_v + 147456;
    ushort_t* w_f1    = w_o + 147456;
    ushort_t* w_f2    = w_f1 + 589824;
    ushort_t* w_lg    = w_f2 + 589824;       // 128*384 (rows 97..127 zero)

    const int M  = B_ * T_;   // 2048
    const int MK = B_ * L_;   // 16384

    // ---- weight conversion (every launch) ----
    cvt(stream, m_in_w,  w_in,  7077888);
    cvt_pad(stream, m_xproj_w, w_xproj, 56, 768, 64, 768, 12);
    cvt_pad(stream, m_dt_w,    w_dt,    768, 24, 768, 64, 12);
    cvt(stream, m_out_w, w_out, 3538944);
    cvt(stream, wq, w_q, 147456);
    cvt(stream, wk, w_k, 147456);
    cvt(stream, wv, w_v, 147456);
    cvt(stream, wo, w_o, 147456);
    cvt(stream, ffn_w1, w_f1, 589824);
    cvt(stream, ffn_w2, w_f2, 589824);
    cvt_pad(stream, out_w, w_lg, 97, 384, 128, 384, 1);

    init_kernel<<<(int)((SZ_BTE + 255) / 256), 256, 0, stream>>>(qe, pos, houtf, residual);

    for (int l = 0; l < ND_; ++l) {
        add_rmsnorm_kernel<<<M, 256, 0, stream>>>(houtf, residual, hidden,
                                                  m_norm_w + (long)l * E_);
        gemm_in_conv<<<dim3(M / 64, 24), 256, 0, stream>>>(
            hidden, w_in + (long)l * 1536 * 384,
            m_conv_w + (long)l * DI_ * DC_, m_conv_b + (long)l * DI_, xz, xc);
        gemm(stream, 0, 1, xc, DI_, w_xproj + (long)l * 64 * 768,
             nullptr, nullptr, dbl, M, 56, 768, 64, 64);
        gemm(stream, 2, 1, dbl, 64, w_dt + (long)l * 768 * 64,
             m_dt_b + (long)l * DI_, nullptr, dtb, M, 768, 64, 768, 768);
        mamba_scan_kernel<<<dim3(DI_ / 256, B_), 256, 0, stream>>>(
            dtb, dbl, xc, xz, m_Alog + (long)l * DI_ * DS_, m_D + (long)l * DI_, yb);
        gemm(stream, 0, 0, yb, DI_, w_out + (long)l * 384 * 768,
             nullptr, nullptr, houtf, M, 384, 768, 384, 384);
    }

    add_rmsnorm_kernel<<<M, 256, 0, stream>>>(houtf, residual, hidden, rms_w);

    gemm(stream, 0, 1, hidden, E_, w_q, bq, nullptr, qh, M, 384, 384, 384, 384);
    cvt(stream, enc, enc_bf, (long)MK * E_);
    gemm(stream, 0, 1, enc_bf, E_, w_k, bk, nullptr, kh, MK, 384, 384, 384, 384);
    gemm(stream, 0, 1, enc_bf, E_, w_v, bv, nullptr, vh, MK, 384, 384, 384, 384);
    attn_kernel<<<B_ * H_, 256, 0, stream>>>(qh, kh, vh, ctx);
    gemm(stream, 0, 0, ctx, E_, w_o, bo, residual, residual, M, 384, 384, 384, 384);

    layernorm_kernel<<<M, 256, 0, stream>>>(residual, ln1_w, ln1_b, hidden);
    gemm(stream, 1, 1, hidden, E_, w_f1, ffn_b1, nullptr, ffnb, M, 1536, 384, 1536, 1536);
    gemm(stream, 0, 0, ffnb, HID_, w_f2, ffn_b2, residual, residual, M, 384, 1536, 384, 384);
    layernorm_kernel<<<M, 256, 0, stream>>>(residual, ln2_w, ln2_b, hidden);

    gemm(stream, 0, 0, hidden, E_, w_lg, out_b, nullptr, (float*)d_out, M, V_, 384, V_, V_);
}

// Round 3
// 984.613 us; speedup vs baseline: 1.4442x; 1.2605x over previous
//
#include <hip/hip_runtime.h>
#include <math.h>

// ---- problem constants ----
constexpr int B_ = 64, L_ = 256, T_ = 32, E_ = 384, H_ = 6;
constexpr int DI_ = 768, DS_ = 16, DC_ = 4, DR_ = 24;
constexpr int HID_ = 1536, V_ = 97, ND_ = 12;
constexpr float EPS_ = 1e-5f;
constexpr int HD_ = 64;

typedef unsigned short ushort_t;
typedef __attribute__((ext_vector_type(8))) short  short8;
typedef __attribute__((ext_vector_type(4))) float  floatx4;
typedef __attribute__((ext_vector_type(8))) unsigned short ushort8v;

__device__ __forceinline__ float siluf(float x) { return x / (1.f + __expf(-x)); }
__device__ __forceinline__ float softplusf(float x) {
    return fmaxf(x, 0.f) + log1pf(expf(-fabsf(x)));
}
__device__ __forceinline__ ushort_t f2bf(float f) {
    unsigned int u = __float_as_uint(f);
    u += 0x7fffu + ((u >> 16) & 1u);
    return (ushort_t)(u >> 16);
}
__device__ __forceinline__ float bf2f(ushort_t u) {
    return __uint_as_float(((unsigned int)u) << 16);
}
__device__ __forceinline__ void unpack2(unsigned int w, float& lo, float& hi) {
    lo = __uint_as_float(w << 16);
    hi = __uint_as_float(w & 0xffff0000u);
}
// async global->LDS, 16B per lane; lds dest = wave-uniform base + lane*16
__device__ __forceinline__ void gl_lds16(const ushort_t* g, ushort_t* l) {
    __builtin_amdgcn_global_load_lds(
        (const __attribute__((address_space(1))) unsigned int*)g,
        (__attribute__((address_space(3))) unsigned int*)l, 16, 0, 0);
}

// ---------------------------------------------------------------------------
// fp32 -> bf16 (vectorized, n divisible by 4)
// ---------------------------------------------------------------------------
__global__ __launch_bounds__(256) void cvt_bf16_kernel(
    const float* __restrict__ src, ushort_t* __restrict__ dst, long n4) {
    long i = (long)blockIdx.x * 256 + threadIdx.x;
    if (i >= n4) return;
    float4 v = ((const float4*)src)[i];
    __attribute__((ext_vector_type(4))) unsigned short o;
    o[0] = f2bf(v.x); o[1] = f2bf(v.y); o[2] = f2bf(v.z); o[3] = f2bf(v.w);
    *(__attribute__((ext_vector_type(4))) unsigned short*)(dst + i * 4) = o;
}

// fp32 -> bf16 with per-layer zero padding
__global__ __launch_bounds__(256) void cvt_pad_kernel(
    const float* __restrict__ src, ushort_t* __restrict__ dst,
    int sr, int sc, int dr, int dc, int layers) {
    long total = (long)layers * dr * dc;
    long idx = (long)blockIdx.x * 256 + threadIdx.x;
    if (idx >= total) return;
    int l = (int)(idx / ((long)dr * dc));
    int rem = (int)(idx % ((long)dr * dc));
    int r = rem / dc, c = rem % dc;
    float v = (r < sr && c < sc) ? src[((long)l * sr + r) * sc + c] : 0.f;
    dst[idx] = f2bf(v);
}

// ---------------------------------------------------------------------------
// bf16 MFMA GEMM with global_load_lds staging + XOR swizzle.
// C[m,n] = act( sum_k A[m,k]*W[n,k] + bias[n] ) + addin ; zero-fill N<=gn<Nz.
// A bf16 [M][lda], W bf16 [Nz_rounded][K]. K % 64 == 0, M % 64 == 0.
// ACT: 0 none, 1 relu, 2 softplus. OBF: 1 bf16 out, 0 fp32 out.
// ---------------------------------------------------------------------------
template <int ACT, int OBF>
__global__ __launch_bounds__(256) void gemm_bf16(
    const ushort_t* __restrict__ A, int lda,
    const ushort_t* __restrict__ W,
    const float* __restrict__ bias,
    const float* __restrict__ addin,
    void* __restrict__ Cv,
    int M, int N, int K, int Nz, int ldc) {
    __shared__ ushort_t As[64 * 64];
    __shared__ ushort_t Bs[64 * 64];

    const int tid = threadIdx.x;
    const int wv = tid >> 6, ln = tid & 63;
    const int bm = blockIdx.x * 64, bn = blockIdx.y * 64;
    const int lm = ln & 15, quad = ln >> 4;
    const int wm = (wv & 1) * 32, wn = (wv >> 1) * 32;
    const int r8 = ln >> 3, c8 = ln & 7;

    floatx4 acc[2][2] = {};

    for (int k0 = 0; k0 < K; k0 += 64) {
#pragma unroll
        for (int j = 0; j < 2; ++j) {
            int row = wv * 16 + j * 8 + r8;
            int cg = c8 ^ (row & 7);
            gl_lds16(A + (size_t)(bm + row) * lda + k0 + cg * 8,
                     &As[(wv * 16 + j * 8) * 64]);
        }
#pragma unroll
        for (int j = 0; j < 2; ++j) {
            int row = wv * 16 + j * 8 + r8;
            int cg = c8 ^ (row & 7);
            gl_lds16(W + (size_t)(bn + row) * K + k0 + cg * 8,
                     &Bs[(wv * 16 + j * 8) * 64]);
        }
        __syncthreads();
#pragma unroll
        for (int ks2 = 0; ks2 < 2; ++ks2) {
            int pc = ((quad + ks2 * 4) ^ (lm & 7)) * 8;
            short8 a0 = *(const short8*)&As[(wm + lm) * 64 + pc];
            short8 a1 = *(const short8*)&As[(wm + 16 + lm) * 64 + pc];
            short8 b0 = *(const short8*)&Bs[(wn + lm) * 64 + pc];
            short8 b1 = *(const short8*)&Bs[(wn + 16 + lm) * 64 + pc];
            acc[0][0] = __builtin_amdgcn_mfma_f32_16x16x32_bf16(a0, b0, acc[0][0], 0, 0, 0);
            acc[0][1] = __builtin_amdgcn_mfma_f32_16x16x32_bf16(a0, b1, acc[0][1], 0, 0, 0);
            acc[1][0] = __builtin_amdgcn_mfma_f32_16x16x32_bf16(a1, b0, acc[1][0], 0, 0, 0);
            acc[1][1] = __builtin_amdgcn_mfma_f32_16x16x32_bf16(a1, b1, acc[1][1], 0, 0, 0);
        }
        __syncthreads();
    }

    // C/D layout: col = lane&15, row = quad*4 + reg  [m89-verified]
#pragma unroll
    for (int sm = 0; sm < 2; ++sm) {
#pragma unroll
        for (int sn = 0; sn < 2; ++sn) {
            const int gn = bn + wn + sn * 16 + lm;
            if (gn >= Nz) continue;
#pragma unroll
            for (int r = 0; r < 4; ++r) {
                const int gm = bm + wm + sm * 16 + quad * 4 + r;
                float v;
                if (gn < N) {
                    v = acc[sm][sn][r];
                    if (bias) v += bias[gn];
                    if (ACT == 1) v = fmaxf(v, 0.f);
                    if (ACT == 2) v = softplusf(v);
                    if (addin) v += addin[(size_t)gm * ldc + gn];
                } else {
                    v = 0.f;
                }
                if (OBF)
                    ((ushort_t*)Cv)[(size_t)gm * ldc + gn] = f2bf(v);
                else
                    ((float*)Cv)[(size_t)gm * ldc + gn] = v;
            }
        }
    }
}

// ---------------------------------------------------------------------------
// in_proj GEMM (M=2048, N=1536, K=384) with FUSED causal conv (DC=4) + SiLU.
// ---------------------------------------------------------------------------
__global__ __launch_bounds__(256) void gemm_in_conv(
    const ushort_t* __restrict__ A,      // hidden bf16 [2048][384]
    const ushort_t* __restrict__ W,      // w_in layer  [1536][384]
    const float* __restrict__ cw,        // conv weight [768][4]
    const float* __restrict__ cb,        // conv bias   [768]
    ushort_t* __restrict__ xz,           // [2048][1536] (z half used)
    ushort_t* __restrict__ xc) {         // [2048][768]
    __shared__ ushort_t As[64 * 64];
    __shared__ ushort_t Bs[64 * 64];
    __shared__ float Cb[64][65];
    __shared__ float Cw[64][4];
    __shared__ float Cbias[64];

    const int tid = threadIdx.x;
    const int wv = tid >> 6, ln = tid & 63;
    const int bm = blockIdx.x * 64, bn = blockIdx.y * 64;
    const int lm = ln & 15, quad = ln >> 4;
    const int wm = (wv & 1) * 32, wn = (wv >> 1) * 32;
    const int r8 = ln >> 3, c8 = ln & 7;
    const bool is_xm = (bn < DI_);

    if (is_xm && tid < 64) {
        *(float4*)&Cw[tid][0] = *(const float4*)&cw[(bn + tid) * 4];
        Cbias[tid] = cb[bn + tid];
    }

    floatx4 acc[2][2] = {};

    for (int k0 = 0; k0 < E_; k0 += 64) {
#pragma unroll
        for (int j = 0; j < 2; ++j) {
            int row = wv * 16 + j * 8 + r8;
            int cg = c8 ^ (row & 7);
            gl_lds16(A + (size_t)(bm + row) * E_ + k0 + cg * 8,
                     &As[(wv * 16 + j * 8) * 64]);
        }
#pragma unroll
        for (int j = 0; j < 2; ++j) {
            int row = wv * 16 + j * 8 + r8;
            int cg = c8 ^ (row & 7);
            gl_lds16(W + (size_t)(bn + row) * E_ + k0 + cg * 8,
                     &Bs[(wv * 16 + j * 8) * 64]);
        }
        __syncthreads();
#pragma unroll
        for (int ks2 = 0; ks2 < 2; ++ks2) {
            int pc = ((quad + ks2 * 4) ^ (lm & 7)) * 8;
            short8 a0 = *(const short8*)&As[(wm + lm) * 64 + pc];
            short8 a1 = *(const short8*)&As[(wm + 16 + lm) * 64 + pc];
            short8 b0 = *(const short8*)&Bs[(wn + lm) * 64 + pc];
            short8 b1 = *(const short8*)&Bs[(wn + 16 + lm) * 64 + pc];
            acc[0][0] = __builtin_amdgcn_mfma_f32_16x16x32_bf16(a0, b0, acc[0][0], 0, 0, 0);
            acc[0][1] = __builtin_amdgcn_mfma_f32_16x16x32_bf16(a0, b1, acc[0][1], 0, 0, 0);
            acc[1][0] = __builtin_amdgcn_mfma_f32_16x16x32_bf16(a1, b0, acc[1][0], 0, 0, 0);
            acc[1][1] = __builtin_amdgcn_mfma_f32_16x16x32_bf16(a1, b1, acc[1][1], 0, 0, 0);
        }
        __syncthreads();
    }

    if (is_xm) {
#pragma unroll
        for (int sm = 0; sm < 2; ++sm)
#pragma unroll
            for (int sn = 0; sn < 2; ++sn)
#pragma unroll
                for (int r = 0; r < 4; ++r)
                    Cb[wm + sm * 16 + quad * 4 + r][wn + sn * 16 + lm] = acc[sm][sn][r];
        __syncthreads();
        const int r = tid >> 2, c0 = (tid & 3) * 16;
        const int tl = r & 31;
        ushort_t pk[16];
#pragma unroll
        for (int j = 0; j < 16; ++j) {
            const int c = c0 + j;
            float a = Cbias[c];
#pragma unroll
            for (int k = 0; k < DC_; ++k) {
                int rr = tl + k - (DC_ - 1);
                if (rr >= 0) a += Cw[c][k] * Cb[r + k - (DC_ - 1)][c];
            }
            pk[j] = f2bf(siluf(a));
        }
        ushort_t* dst = xc + (size_t)(bm + r) * DI_ + bn + c0;
        *(ushort8v*)dst = *(ushort8v*)&pk[0];
        *(ushort8v*)(dst + 8) = *(ushort8v*)&pk[8];
    } else {
#pragma unroll
        for (int sm = 0; sm < 2; ++sm)
#pragma unroll
            for (int sn = 0; sn < 2; ++sn) {
                const int gn = bn + wn + sn * 16 + lm;
#pragma unroll
                for (int r = 0; r < 4; ++r) {
                    const int gm = bm + wm + sm * 16 + quad * 4 + r;
                    xz[(size_t)gm * 1536 + gn] = f2bf(acc[sm][sn][r]);
                }
            }
    }
}

// ---------------------------------------------------------------------------
// FUSED xproj GEMM + dt projection/softplus + selective scan.
// grid (3, 64): blockIdx.y = batch b, blockIdx.x = 256-channel chunk.
// Stage xc[b] (32x768 bf16, XOR-swizzled per 64-col chunk) in LDS; compute
// dbl[32][56] = xc[b] @ w_xproj^T via MFMA into fp32 LDS (redundant x3);
// then thread d does dt = softplus(dot24(dbl[t], dt_w[d]) + dt_b[d]) and the
// 32-step scan with B/C broadcast from fp32 dbl.
// ---------------------------------------------------------------------------
__global__ __launch_bounds__(256) void xproj_dt_scan_kernel(
    const ushort_t* __restrict__ xc,      // [2048][768] bf16
    const ushort_t* __restrict__ xz,      // [2048][1536] bf16 (z half)
    const ushort_t* __restrict__ w_xproj, // layer: [64][768] bf16 (rows 56.. zero)
    const float* __restrict__ dt_w,       // layer: [768][24] fp32
    const float* __restrict__ dt_b,       // layer: [768]
    const float* __restrict__ Alog,       // layer: [768][16]
    const float* __restrict__ Dp,         // layer: [768]
    ushort_t* __restrict__ y) {           // [2048][768] bf16
    __shared__ ushort_t Xs[32 * 768];     // 48 KB, swizzled
    __shared__ float Dbl[32][64];         // 8 KB fp32

    const int tid = threadIdx.x;
    const int wv = tid >> 6, ln = tid & 63;
    const int b = blockIdx.y;
    const int lm = ln & 15, quad = ln >> 4;
    const int r8 = ln >> 3, c8 = ln & 7;

    // ---- stage xc[b] (32 rows x 768 cols) into LDS, gemm-style swizzle ----
#pragma unroll
    for (int i = 0; i < 12; ++i) {
        int q = wv * 96 + i * 8 + r8;   // pair index = row*12 + chunk
        int row = q / 12, chunk = q % 12;
        int cg = c8 ^ (row & 7);
        gl_lds16(xc + (size_t)(b * T_ + row) * DI_ + chunk * 64 + cg * 8,
                 &Xs[(wv * 96 + i * 8) * 64]);
    }
    __syncthreads();

    // ---- xproj MFMA: wave wv -> m-tile (wv&1), n-tiles {wv>>1, (wv>>1)+2} ----
    {
        const int mt = wv & 1, nt0 = wv >> 1;
        floatx4 a0 = {}, a1 = {};
        const int arow = mt * 16 + lm;
#pragma unroll
        for (int ks = 0; ks < 24; ++ks) {
            int og = (((ks & 1) * 4 + quad) ^ (arow & 7)) * 8;
            short8 av = *(const short8*)&Xs[(arow * 12 + (ks >> 1)) * 64 + og];
            short8 b0 = *(const short8*)(w_xproj + (size_t)(nt0 * 16 + lm) * DI_ +
                                         ks * 32 + quad * 8);
            short8 b1 = *(const short8*)(w_xproj + (size_t)((nt0 + 2) * 16 + lm) * DI_ +
                                         ks * 32 + quad * 8);
            a0 = __builtin_amdgcn_mfma_f32_16x16x32_bf16(av, b0, a0, 0, 0, 0);
            a1 = __builtin_amdgcn_mfma_f32_16x16x32_bf16(av, b1, a1, 0, 0, 0);
        }
#pragma unroll
        for (int r = 0; r < 4; ++r) {
            Dbl[mt * 16 + quad * 4 + r][nt0 * 16 + lm] = a0[r];
            Dbl[mt * 16 + quad * 4 + r][(nt0 + 2) * 16 + lm] = a1[r];
        }
    }
    __syncthreads();

    // ---- dt + scan: thread owns channel d ----
    const int d = blockIdx.x * 256 + tid;
    float wdt[DR_];
#pragma unroll
    for (int r = 0; r < DR_; ++r) wdt[r] = dt_w[(size_t)d * DR_ + r];
    const float dtb_v = dt_b[d];
    float Aa[DS_];
#pragma unroll
    for (int s = 0; s < DS_; ++s) Aa[s] = -expf(Alog[(size_t)d * DS_ + s]);
    const float Dv = Dp[d];
    float h[DS_] = {};

    const int chunk64 = d >> 6, off = d & 63, elem = off & 7;
    for (int t = 0; t < T_; ++t) {
        // dt = softplus(dot24 + bias)
        float dtv = dtb_v;
#pragma unroll
        for (int r4 = 0; r4 < DR_ / 4; ++r4) {
            float4 dv = *(const float4*)&Dbl[t][r4 * 4];
            dtv += dv.x * wdt[r4 * 4] + dv.y * wdt[r4 * 4 + 1] +
                   dv.z * wdt[r4 * 4 + 2] + dv.w * wdt[r4 * 4 + 3];
        }
        dtv = softplusf(dtv);

        // xc value from swizzled LDS
        int og = ((off >> 3) ^ (t & 7)) * 8;
        float xcv = bf2f(Xs[(t * 12 + chunk64) * 64 + og + elem]);

        float acc = 0.f;
#pragma unroll
        for (int s4 = 0; s4 < DS_ / 4; ++s4) {
            float4 Bv = *(const float4*)&Dbl[t][DR_ + s4 * 4];
            float4 Cv = *(const float4*)&Dbl[t][DR_ + DS_ + s4 * 4];
#pragma unroll
            for (int j = 0; j < 4; ++j) {
                int s = s4 * 4 + j;
                float Bvj = (j == 0) ? Bv.x : (j == 1) ? Bv.y : (j == 2) ? Bv.z : Bv.w;
                float Cvj = (j == 0) ? Cv.x : (j == 1) ? Cv.y : (j == 2) ? Cv.z : Cv.w;
                h[s] = __expf(dtv * Aa[s]) * h[s] + dtv * Bvj * xcv;
                acc += h[s] * Cvj;
            }
        }
        float zv = bf2f(xz[(size_t)(b * T_ + t) * (2 * DI_) + DI_ + d]);
        y[(size_t)(b * T_ + t) * DI_ + d] = f2bf((acc + Dv * xcv) * siluf(zv));
    }
}

// ---------------------------------------------------------------------------
__global__ void init_kernel(const float* __restrict__ qe,
                            const float* __restrict__ pos,
                            float* __restrict__ houtf,
                            float* __restrict__ residual) {
    long idx = (long)blockIdx.x * 256 + threadIdx.x;
    if (idx >= (long)B_ * T_ * E_) return;
    int te = (int)(idx % ((long)T_ * E_));
    houtf[idx] = qe[te] + pos[te];
    residual[idx] = 0.f;
}

// residual += hin; hidden_bf = bf16(rmsnorm(residual) * w)  (shuffle reduce)
__global__ __launch_bounds__(256) void add_rmsnorm_kernel(
    const float* __restrict__ hin, float* __restrict__ residual,
    ushort_t* __restrict__ hout, const float* __restrict__ w) {
    const int row = blockIdx.x, tid = threadIdx.x;
    const long base = (long)row * E_;
    __shared__ float ws[4];

    float x0 = hin[base + tid] + residual[base + tid];
    bool has1 = (tid + 256 < E_);
    float x1 = has1 ? hin[base + tid + 256] + residual[base + tid + 256] : 0.f;
    residual[base + tid] = x0;
    if (has1) residual[base + tid + 256] = x1;

    float p = x0 * x0 + x1 * x1;
#pragma unroll
    for (int m = 1; m < 64; m <<= 1) p += __shfl_xor(p, m, 64);
    if ((tid & 63) == 0) ws[tid >> 6] = p;
    __syncthreads();
    float sc = rsqrtf((ws[0] + ws[1] + ws[2] + ws[3]) / E_ + EPS_);
    hout[base + tid] = f2bf(x0 * sc * w[tid]);
    if (has1) hout[base + tid + 256] = f2bf(x1 * sc * w[tid + 256]);
}

// layernorm fp32 in -> bf16 out (shuffle reduce)
__global__ __launch_bounds__(256) void layernorm_kernel(
    const float* __restrict__ x, const float* __restrict__ w,
    const float* __restrict__ b, ushort_t* __restrict__ out) {
    const int row = blockIdx.x, tid = threadIdx.x;
    const long base = (long)row * E_;
    __shared__ float wa[4], wb[4];

    float x0 = x[base + tid];
    bool has1 = (tid + 256 < E_);
    float x1 = has1 ? x[base + tid + 256] : 0.f;

    float p = x0 + x1;
#pragma unroll
    for (int m = 1; m < 64; m <<= 1) p += __shfl_xor(p, m, 64);
    if ((tid & 63) == 0) wa[tid >> 6] = p;
    __syncthreads();
    float mu = (wa[0] + wa[1] + wa[2] + wa[3]) / E_;

    float d0 = x0 - mu, d1 = has1 ? x1 - mu : 0.f;
    float q = d0 * d0 + d1 * d1;
#pragma unroll
    for (int m = 1; m < 64; m <<= 1) q += __shfl_xor(q, m, 64);
    if ((tid & 63) == 0) wb[tid >> 6] = q;
    __syncthreads();
    float sc = rsqrtf((wb[0] + wb[1] + wb[2] + wb[3]) / E_ + EPS_);
    out[base + tid] = f2bf(d0 * sc * w[tid] + b[tid]);
    if (has1) out[base + tid + 256] = f2bf(d1 * sc * w[tid + 256] + b[tid + 256]);
}

// ---------------------------------------------------------------------------
// cross-attention, MFMA version: one block per (b,h), 4 waves.
// ---------------------------------------------------------------------------
__global__ __launch_bounds__(256) void attn_kernel(
    const ushort_t* __restrict__ qh,
    const ushort_t* __restrict__ kh,
    const ushort_t* __restrict__ vh,
    ushort_t* __restrict__ ctx) {
    const int h = blockIdx.x % H_;
    const int b = blockIdx.x / H_;
    const int tid = threadIdx.x;
    const int w = tid >> 6, ln = tid & 63;
    const int lm = ln & 15, quad = ln >> 4;

    __shared__ __attribute__((aligned(16))) ushort_t Vt[64 * 264];  // [d][s]
    __shared__ __attribute__((aligned(16))) ushort_t Pb[32 * 264];  // [t][s]
    __shared__ float rmax[4][32];
    __shared__ float rsum[4][32];

    short8 aq[2][2];
#pragma unroll
    for (int mt = 0; mt < 2; ++mt)
#pragma unroll
        for (int ks = 0; ks < 2; ++ks)
            aq[mt][ks] = *(const short8*)(qh + (size_t)(b * T_ + mt * 16 + lm) * E_ +
                                          h * HD_ + ks * 32 + quad * 8);

    short8 bk[4][2];
#pragma unroll
    for (int nt = 0; nt < 4; ++nt)
#pragma unroll
        for (int ks = 0; ks < 2; ++ks)
            bk[nt][ks] = *(const short8*)(kh + (size_t)(b * L_ + w * 64 + nt * 16 + lm) * E_ +
                                          h * HD_ + ks * 32 + quad * 8);

    {
        const int sp = tid & 127, dh = tid >> 7;
        const int s0 = sp * 2;
        const ushort_t* vr = vh + (size_t)(b * L_ + s0) * E_ + h * HD_ + dh * 32;
        uint4 va[4], vb[4];
#pragma unroll
        for (int c = 0; c < 4; ++c) {
            va[c] = *(const uint4*)(vr + c * 8);
            vb[c] = *(const uint4*)(vr + E_ + c * 8);
        }
#pragma unroll
        for (int c = 0; c < 4; ++c) {
            const unsigned int* pa = (const unsigned int*)&va[c];
            const unsigned int* pb = (const unsigned int*)&vb[c];
#pragma unroll
            for (int j = 0; j < 4; ++j) {
                int d0 = dh * 32 + c * 8 + j * 2;
                unsigned int lo = (pa[j] & 0xffffu) | (pb[j] << 16);
                unsigned int hi = (pa[j] >> 16) | (pb[j] & 0xffff0000u);
                *(unsigned int*)&Vt[d0 * 264 + s0] = lo;
                *(unsigned int*)&Vt[(d0 + 1) * 264 + s0] = hi;
            }
        }
    }

    floatx4 acc[2][4] = {};
#pragma unroll
    for (int ks = 0; ks < 2; ++ks)
#pragma unroll
        for (int mt = 0; mt < 2; ++mt)
#pragma unroll
            for (int nt = 0; nt < 4; ++nt)
                acc[mt][nt] = __builtin_amdgcn_mfma_f32_16x16x32_bf16(
                    aq[mt][ks], bk[nt][ks], acc[mt][nt], 0, 0, 0);
#pragma unroll
    for (int mt = 0; mt < 2; ++mt)
#pragma unroll
        for (int nt = 0; nt < 4; ++nt)
            acc[mt][nt] *= 0.125f;

    float mpart[2][4];
#pragma unroll
    for (int mt = 0; mt < 2; ++mt)
#pragma unroll
        for (int r = 0; r < 4; ++r) {
            float m = fmaxf(fmaxf(acc[mt][0][r], acc[mt][1][r]),
                            fmaxf(acc[mt][2][r], acc[mt][3][r]));
#pragma unroll
            for (int mk = 1; mk < 16; mk <<= 1)
                m = fmaxf(m, __shfl_xor(m, mk, 64));
            mpart[mt][r] = m;
        }
    if (lm == 0) {
#pragma unroll
        for (int mt = 0; mt < 2; ++mt)
#pragma unroll
            for (int r = 0; r < 4; ++r)
                rmax[w][mt * 16 + quad * 4 + r] = mpart[mt][r];
    }
    __syncthreads();

    float spart[2][4];
#pragma unroll
    for (int mt = 0; mt < 2; ++mt)
#pragma unroll
        for (int r = 0; r < 4; ++r) {
            const int t = mt * 16 + quad * 4 + r;
            float gm = fmaxf(fmaxf(rmax[0][t], rmax[1][t]),
                             fmaxf(rmax[2][t], rmax[3][t]));
            float s = 0.f;
#pragma unroll
            for (int nt = 0; nt < 4; ++nt) {
                float e = __expf(acc[mt][nt][r] - gm);
                s += e;
                Pb[t * 264 + w * 64 + nt * 16 + lm] = f2bf(e);
            }
#pragma unroll
            for (int mk = 1; mk < 16; mk <<= 1)
                s += __shfl_xor(s, mk, 64);
            spart[mt][r] = s;
        }
    if (lm == 0) {
#pragma unroll
        for (int mt = 0; mt < 2; ++mt)
#pragma unroll
            for (int r = 0; r < 4; ++r)
                rsum[w][mt * 16 + quad * 4 + r] = spart[mt][r];
    }
    __syncthreads();

    const int mt = w & 1, nth = w >> 1;
    floatx4 pacc[2] = {};
#pragma unroll
    for (int ks = 0; ks < 8; ++ks) {
        short8 pa = *(const short8*)&Pb[(mt * 16 + lm) * 264 + ks * 32 + quad * 8];
#pragma unroll
        for (int i = 0; i < 2; ++i) {
            short8 vb = *(const short8*)&Vt[((nth * 2 + i) * 16 + lm) * 264 + ks * 32 + quad * 8];
            pacc[i] = __builtin_amdgcn_mfma_f32_16x16x32_bf16(pa, vb, pacc[i], 0, 0, 0);
        }
    }

#pragma unroll
    for (int r = 0; r < 4; ++r) {
        const int t = mt * 16 + quad * 4 + r;
        float dn = 1.f / (rsum[0][t] + rsum[1][t] + rsum[2][t] + rsum[3][t]);
#pragma unroll
        for (int i = 0; i < 2; ++i) {
            const int d = (nth * 2 + i) * 16 + lm;
            ctx[(size_t)(b * T_ + t) * E_ + h * HD_ + d] = f2bf(pacc[i][r] * dn);
        }
    }
}

// ---------------------------------------------------------------------------
static void gemm(hipStream_t s, int act, int obf, const ushort_t* A, int lda,
                 const ushort_t* W, const float* bias, const float* addin,
                 void* C, int M, int N, int K, int Nz, int ldc) {
    dim3 g(M / 64, (Nz + 63) / 64), b(256);
    if (obf) {
        switch (act) {
            case 0: gemm_bf16<0, 1><<<g, b, 0, s>>>(A, lda, W, bias, addin, C, M, N, K, Nz, ldc); break;
            case 1: gemm_bf16<1, 1><<<g, b, 0, s>>>(A, lda, W, bias, addin, C, M, N, K, Nz, ldc); break;
            case 2: gemm_bf16<2, 1><<<g, b, 0, s>>>(A, lda, W, bias, addin, C, M, N, K, Nz, ldc); break;
        }
    } else {
        gemm_bf16<0, 0><<<g, b, 0, s>>>(A, lda, W, bias, addin, C, M, N, K, Nz, ldc);
    }
}

static void cvt(hipStream_t s, const float* src, ushort_t* dst, long n) {
    long n4 = n / 4;
    cvt_bf16_kernel<<<(int)((n4 + 255) / 256), 256, 0, s>>>(src, dst, n4);
}
static void cvt_pad(hipStream_t s, const float* src, ushort_t* dst,
                    int sr, int sc, int dr, int dc, int layers) {
    long total = (long)layers * dr * dc;
    cvt_pad_kernel<<<(int)((total + 255) / 256), 256, 0, s>>>(src, dst, sr, sc, dr, dc, layers);
}

extern "C" void kernel_launch(void* const* d_in, const int* in_sizes, int n_in,
                              void* d_out, int out_size, void* d_ws, size_t ws_size,
                              hipStream_t stream) {
    const float* enc      = (const float*)d_in[0];
    const float* qe       = (const float*)d_in[1];
    const float* pos      = (const float*)d_in[2];
    const float* m_norm_w = (const float*)d_in[3];
    const float* m_in_w   = (const float*)d_in[4];
    const float* m_conv_w = (const float*)d_in[5];
    const float* m_conv_b = (const float*)d_in[6];
    const float* m_xproj_w= (const float*)d_in[7];
    const float* m_dt_w   = (const float*)d_in[8];
    const float* m_dt_b   = (const float*)d_in[9];
    const float* m_Alog   = (const float*)d_in[10];
    const float* m_D      = (const float*)d_in[11];
    const float* m_out_w  = (const float*)d_in[12];
    const float* rms_w    = (const float*)d_in[13];
    const float* wq = (const float*)d_in[14];
    const float* bq = (const float*)d_in[15];
    const float* wk = (const float*)d_in[16];
    const float* bk = (const float*)d_in[17];
    const float* wv = (const float*)d_in[18];
    const float* bv = (const float*)d_in[19];
    const float* wo = (const float*)d_in[20];
    const float* bo = (const float*)d_in[21];
    const float* ln1_w = (const float*)d_in[22];
    const float* ln1_b = (const float*)d_in[23];
    const float* ffn_w1 = (const float*)d_in[24];
    const float* ffn_b1 = (const float*)d_in[25];
    const float* ffn_w2 = (const float*)d_in[26];
    const float* ffn_b2 = (const float*)d_in[27];
    const float* ln2_w = (const float*)d_in[28];
    const float* ln2_b = (const float*)d_in[29];
    const float* out_w = (const float*)d_in[30];
    const float* out_b = (const float*)d_in[31];

    const long SZ_BTE = (long)B_ * T_ * E_;  // 786432
    float* residual = (float*)d_ws;
    float* houtf    = residual + SZ_BTE;

    ushort_t* u = (ushort_t*)(houtf + SZ_BTE);
    ushort_t* hidden = u;                    // 786,432
    ushort_t* S      = hidden + SZ_BTE;      // union region
    // mamba-phase layout:
    ushort_t* xz  = S;                       // 3,145,728
    ushort_t* xc  = xz + 3145728;            // 1,572,864
    ushort_t* yb  = xc + 1572864;            // 1,572,864
    // attention-phase aliases:
    ushort_t* enc_bf = S;                    // 6,291,456
    ushort_t* qh  = S + 6291456;             //   786,432
    ushort_t* ctx = qh + 786432;             //   786,432
    // ffn alias:
    ushort_t* ffnb = S;                      // 3,145,728
    ushort_t* kh = S + 7995392;              // 6,291,456
    ushort_t* vh = kh + 6291456;             // 6,291,456

    // bf16 weights (padded where needed)
    ushort_t* w_in    = vh + 6291456;        // 7,077,888
    ushort_t* w_xproj = w_in + 7077888;      // 12*64*768 (rows 56..63 zero)
    ushort_t* w_out   = w_xproj + 589824;    // 3,538,944
    ushort_t* w_q     = w_out + 3538944;
    ushort_t* w_k     = w_q + 147456;
    ushort_t* w_v     = w_k + 147456;
    ushort_t* w_o     = w_v + 147456;
    ushort_t* w_f1    = w_o + 147456;
    ushort_t* w_f2    = w_f1 + 589824;
    ushort_t* w_lg    = w_f2 + 589824;       // 128*384 (rows 97..127 zero)

    const int M  = B_ * T_;   // 2048
    const int MK = B_ * L_;   // 16384

    // ---- weight conversion (every launch) ----
    cvt(stream, m_in_w,  w_in,  7077888);
    cvt_pad(stream, m_xproj_w, w_xproj, 56, 768, 64, 768, 12);
    cvt(stream, m_out_w, w_out, 3538944);
    cvt(stream, wq, w_q, 147456);
    cvt(stream, wk, w_k, 147456);
    cvt(stream, wv, w_v, 147456);
    cvt(stream, wo, w_o, 147456);
    cvt(stream, ffn_w1, w_f1, 589824);
    cvt(stream, ffn_w2, w_f2, 589824);
    cvt_pad(stream, out_w, w_lg, 97, 384, 128, 384, 1);

    init_kernel<<<(int)((SZ_BTE + 255) / 256), 256, 0, stream>>>(qe, pos, houtf, residual);

    for (int l = 0; l < ND_; ++l) {
        add_rmsnorm_kernel<<<M, 256, 0, stream>>>(houtf, residual, hidden,
                                                  m_norm_w + (long)l * E_);
        gemm_in_conv<<<dim3(M / 64, 24), 256, 0, stream>>>(
            hidden, w_in + (long)l * 1536 * 384,
            m_conv_w + (long)l * DI_ * DC_, m_conv_b + (long)l * DI_, xz, xc);
        xproj_dt_scan_kernel<<<dim3(3, B_), 256, 0, stream>>>(
            xc, xz, w_xproj + (long)l * 64 * 768,
            m_dt_w + (long)l * DI_ * DR_, m_dt_b + (long)l * DI_,
            m_Alog + (long)l * DI_ * DS_, m_D + (long)l * DI_, yb);
        gemm(stream, 0, 0, yb, DI_, w_out + (long)l * 384 * 768,
             nullptr, nullptr, houtf, M, 384, 768, 384, 384);
    }

    add_rmsnorm_kernel<<<M, 256, 0, stream>>>(houtf, residual, hidden, rms_w);

    gemm(stream, 0, 1, hidden, E_, w_q, bq, nullptr, qh, M, 384, 384, 384, 384);
    cvt(stream, enc, enc_bf, (long)MK * E_);
    gemm(stream, 0, 1, enc_bf, E_, w_k, bk, nullptr, kh, MK, 384, 384, 384, 384);
    gemm(stream, 0, 1, enc_bf, E_, w_v, bv, nullptr, vh, MK, 384, 384, 384, 384);
    attn_kernel<<<B_ * H_, 256, 0, stream>>>(qh, kh, vh, ctx);
    gemm(stream, 0, 0, ctx, E_, w_o, bo, residual, residual, M, 384, 384, 384, 384);

    layernorm_kernel<<<M, 256, 0, stream>>>(residual, ln1_w, ln1_b, hidden);
    gemm(stream, 1, 1, hidden, E_, w_f1, ffn_b1, nullptr, ffnb, M, 1536, 384, 1536, 1536);
    gemm(stream, 0, 0, ffnb, HID_, w_f2, ffn_b2, residual, residual, M, 384, 1536, 384, 384);
    layernorm_kernel<<<M, 256, 0, stream>>>(residual, ln2_w, ln2_b, hidden);

    gemm(stream, 0, 0, hidden, E_, w_lg, out_b, nullptr, (float*)d_out, M, V_, 384, V_, V_);
}